// Round 7
// baseline (521.355 us; speedup 1.0000x reference)
//
#include <hip/hip_runtime.h>
#include <hip/hip_bf16.h>
#include <stdint.h>

#define B_ 2
#define S_ 4096
#define DM 1024
#define H_ 16
#define HD 64
#define M_TOT (B_*S_)   // 8192

typedef unsigned short u16;
typedef short s16x8 __attribute__((ext_vector_type(8)));
typedef short s16x4 __attribute__((ext_vector_type(4)));
typedef float f32x4 __attribute__((ext_vector_type(4)));
typedef uint32_t u32x2 __attribute__((ext_vector_type(2)));

// ---- mfma_f32_16x16x16_bf16 (K=16) ----
#if __has_builtin(__builtin_amdgcn_mfma_f32_16x16x16_bf16)
#define MFMA16(A,B,C) __builtin_amdgcn_mfma_f32_16x16x16_bf16(A,B,C,0,0,0)
#elif __has_builtin(__builtin_amdgcn_mfma_f32_16x16x16bf16_1k)
#define MFMA16(A,B,C) __builtin_amdgcn_mfma_f32_16x16x16bf16_1k(A,B,C,0,0,0)
#else
static __device__ __forceinline__ f32x4 mfma16_asm(s16x4 a, s16x4 b, f32x4 c){
  f32x4 d;
  asm volatile("v_mfma_f32_16x16x16_bf16 %0, %1, %2, %3" : "=v"(d) : "v"(a), "v"(b), "v"(c));
  return d;
}
#define MFMA16(A,B,C) mfma16_asm(A,B,C)
#endif

__device__ __forceinline__ u16 f2bf(float f){
  union { float fv; uint32_t u; } x; x.fv = f;
  uint32_t r = (x.u + 0x7fffu + ((x.u >> 16) & 1u)) >> 16;
  return (u16)r;
}

// pack two f32 -> bf16x2 (a -> low 16, b -> high 16)
#if __has_builtin(__builtin_amdgcn_cvt_pk_bf16_f32)
typedef __bf16 bf16x2_t __attribute__((ext_vector_type(2)));
__device__ __forceinline__ uint32_t pkbf(float a, float b){
  union { bf16x2_t v; uint32_t u; } x;
  x.v = __builtin_amdgcn_cvt_pk_bf16_f32(a, b);
  return x.u;
}
#else
__device__ __forceinline__ uint32_t pkbf(float a, float b){
  union { float f; uint32_t u; } xa, xb; xa.f = a; xb.f = b;
  return __builtin_amdgcn_perm(xb.u + 0x8000u, xa.u + 0x8000u, 0x07060302u);
}
#endif

__device__ __forceinline__ void gld_lds16(const void* g, void* l){
  __builtin_amdgcn_global_load_lds((const __attribute__((address_space(1))) void*)g,
                                   (__attribute__((address_space(3))) void*)l, 16, 0, 0);
}

// ---------------- convert x (fp32) -> bf16 ----------------
__global__ __launch_bounds__(256) void k_cvt_x(const float* __restrict__ x, u16* __restrict__ xb){
  size_t i = (size_t)blockIdx.x * 256 + threadIdx.x;
  const float4* p = (const float4*)x + i*2;
  float4 a = p[0], b = p[1];
  union { u16 u[8]; uint4 v; } o;
  o.u[0]=f2bf(a.x); o.u[1]=f2bf(a.y); o.u[2]=f2bf(a.z); o.u[3]=f2bf(a.w);
  o.u[4]=f2bf(b.x); o.u[5]=f2bf(b.y); o.u[6]=f2bf(b.z); o.u[7]=f2bf(b.w);
  ((uint4*)xb)[i] = o.v;
}

// ------- transpose + convert W [K][N] f32 -> WT [N][K] bf16 (4 mats) -------
__global__ __launch_bounds__(256) void k_wt(const float* __restrict__ W0, const float* __restrict__ W1,
                                            const float* __restrict__ W2, const float* __restrict__ W3,
                                            u16* __restrict__ wt){
  const float* W = blockIdx.z==0?W0: blockIdx.z==1?W1: blockIdx.z==2?W2:W3;
  u16* out = wt + (size_t)blockIdx.z * DM * DM;
  int n0 = blockIdx.x*64, k0 = blockIdx.y*64;
  __shared__ u16 T[64*66];
  int t = threadIdx.x;
  #pragma unroll
  for (int i=0;i<4;i++){
    int idx = t + i*256;
    int kr = idx >> 4, n4 = idx & 15;
    float4 v = *(const float4*)(W + (size_t)(k0+kr)*DM + n0 + n4*4);
    T[(n4*4+0)*66 + kr] = f2bf(v.x);
    T[(n4*4+1)*66 + kr] = f2bf(v.y);
    T[(n4*4+2)*66 + kr] = f2bf(v.z);
    T[(n4*4+3)*66 + kr] = f2bf(v.w);
  }
  __syncthreads();
  #pragma unroll
  for (int i=0;i<2;i++){
    int idx = t + i*256;
    int n = idx >> 3, k8 = idx & 7;
    union { u16 u[8]; uint4 v; } o;
    #pragma unroll
    for (int j=0;j<8;j++) o.u[j] = T[n*66 + k8*8 + j];
    *(uint4*)(out + (size_t)(n0+n)*DM + k0 + k8*8) = o.v;
  }
}

// ---------------- 128x128 MFMA GEMM, A[M,K] bf16 row-major, BT[N,K] bf16 ----------------
__device__ __forceinline__ void gemm128(const u16* __restrict__ A, const u16* __restrict__ BT,
                                        const float* __restrict__ bias, float scale,
                                        u16* __restrict__ outb, float* __restrict__ outf,
                                        int m0, int n0){
  __shared__ __align__(16) u16 As[128*32];
  __shared__ __align__(16) u16 Bs[128*32];
  int t = threadIdx.x;
  int lane = t & 63, w = t >> 6;
  int wm = w & 1, wn = w >> 1;
  int c16 = lane & 15, quad = lane >> 4;
  f32x4 acc[4][4] = {};
  for (int k0 = 0; k0 < DM; k0 += 32){
    #pragma unroll
    for (int i=0;i<2;i++){
      int idx = t + i*256;
      int row = idx >> 2, c8 = (idx & 3) << 3;
      gld_lds16(A  + (size_t)(m0+row)*DM + k0 + c8, &As[idx*8]);
      gld_lds16(BT + (size_t)(n0+row)*DM + k0 + c8, &Bs[idx*8]);
    }
    __syncthreads();
    s16x8 af[4], bf[4];
    #pragma unroll
    for (int mi=0;mi<4;mi++) af[mi] = *(const s16x8*)&As[(wm*64+mi*16+c16)*32 + quad*8];
    #pragma unroll
    for (int ni=0;ni<4;ni++) bf[ni] = *(const s16x8*)&Bs[(wn*64+ni*16+c16)*32 + quad*8];
    #pragma unroll
    for (int mi=0;mi<4;mi++)
      #pragma unroll
      for (int ni=0;ni<4;ni++)
        acc[mi][ni] = __builtin_amdgcn_mfma_f32_16x16x32_bf16(af[mi], bf[ni], acc[mi][ni], 0, 0, 0);
    __syncthreads();
  }
  #pragma unroll
  for (int mi=0;mi<4;mi++){
    #pragma unroll
    for (int ni=0;ni<4;ni++){
      int col = n0 + wn*64 + ni*16 + c16;
      float bc = bias[col];
      #pragma unroll
      for (int r=0;r<4;r++){
        int row = m0 + wm*64 + mi*16 + quad*4 + r;
        float v = (acc[mi][ni][r] + bc) * scale;
        if (outb) outb[(size_t)row*DM + col] = f2bf(v);
        else      outf[(size_t)row*DM + col] = v;
      }
    }
  }
}

#define CL2 0.18033688011112042f   // log2(e)/sqrt(64)

__global__ __launch_bounds__(256) void k_gemm_qkv(const u16* __restrict__ xb, const u16* __restrict__ wt,
                                                  const float* __restrict__ b0, const float* __restrict__ b1,
                                                  const float* __restrict__ b2,
                                                  u16* __restrict__ q, u16* __restrict__ k, u16* __restrict__ v){
  int z = blockIdx.z;
  const u16* BT = wt + (size_t)z*DM*DM;
  const float* bias = z==0?b0: z==1?b1:b2;
  u16* out = z==0?q: z==1?k:v;
  float scale = (z==0) ? CL2 : 1.0f;   // fold softmax scale+log2e into Q
  gemm128(xb, BT, bias, scale, out, nullptr, blockIdx.y*128, blockIdx.x*128);
}

__global__ __launch_bounds__(256) void k_gemm_out(const u16* __restrict__ ab, const u16* __restrict__ wto,
                                                  const float* __restrict__ bias, float* __restrict__ out){
  gemm128(ab, wto, bias, 1.0f, nullptr, out, blockIdx.y*128, blockIdx.x*128);
}

// ---------------- transpose V [B*S, H*64] -> VT [B,H,64,S] ----------------
__global__ __launch_bounds__(256) void k_vt(const u16* __restrict__ vb, u16* __restrict__ vt){
  __shared__ u16 T[64*66];   // [d][s]
  int s0 = blockIdx.x*64, h = blockIdx.y, b = blockIdx.z;
  int t = threadIdx.x;
  #pragma unroll
  for (int i=0;i<2;i++){
    int idx = t + i*256;
    int sr = idx >> 3, d8 = idx & 7;
    s16x8 v = *(const s16x8*)(vb + ((size_t)(b*S_ + s0 + sr))*DM + h*64 + d8*8);
    #pragma unroll
    for (int j=0;j<8;j++) T[(d8*8+j)*66 + sr] = ((const u16*)&v)[j];
  }
  __syncthreads();
  #pragma unroll
  for (int i=0;i<2;i++){
    int idx = t + i*256;
    int d = idx >> 3, s8 = idx & 7;
    union { u16 u[8]; uint4 v; } o;
    #pragma unroll
    for (int j=0;j<8;j++) o.u[j] = T[d*66 + s8*8 + j];
    *(uint4*)(vt + ((size_t)((b*H_ + h)*64 + d))*S_ + s0 + s8*8) = o.v;
  }
}

// ---------------- flash attention v7 ----------------
// = round-3 control flow (best measured: 512 thr, Q-tile 256, simple 2-barrier
//   staging, NO register prefetch / ping-pong — compiler schedules it best)
// + VALU diet (CL2 pre-folded into Q; v_cvt_pk_bf16_f32 pack)
// + LDS-conflict diet from r6 (K stride 68; V interleaved b128 layout,
//   measured conflicts /5). Wave (qq=w&3, kh=w>>2): 64q x 64kv.
#define KST 68
#define VST 132
__global__ __launch_bounds__(512, 2) void k_attn(const u16* __restrict__ qg, const u16* __restrict__ kg,
                                                 const u16* __restrict__ vtg, u16* __restrict__ ao){
  __shared__ __align__(16) char smem[38912];
  u16*   Kb  = (u16*)smem;                 // [128 kv][KST] 17408 B
  u16*   Vb  = (u16*)(smem + 17408);       // [64 d][VST] interleaved, 16896 B
  float* Ob  = (float*)smem;               // [256 q][36] f32 (epilogue)
  u16*   ObT = (u16*)smem;                 // [256 q][72]    (epilogue)
  float* Lb  = (float*)(smem + 36864);     // [2][256]

  int t = threadIdx.x, lane = t & 63, w = t >> 6;
  int c16 = lane & 15, quad = lane >> 4;
  int qq = w & 3, kh = w >> 2;
  int h = blockIdx.y, b = blockIdx.z;
  int q0 = blockIdx.x * 256;
  size_t rowbase = (size_t)b * S_;
  const u16* vbase = vtg + ((size_t)(b*H_ + h)) * 64 * S_;

  // persistent Q B-frags (pre-scaled by CL2): q = q0+qq*64+nt*16+c16, k = ks*32+quad*8
  s16x8 qf[4][2];
  #pragma unroll
  for (int nt=0;nt<4;nt++)
    #pragma unroll
    for (int ks=0;ks<2;ks++)
      qf[nt][ks] = *(const s16x8*)(qg + (rowbase + q0 + qq*64 + nt*16 + c16)*DM + h*64 + ks*32 + quad*8);

  // oacc[dt][nt]: O^T[d=dt*16+quad*4+r][q=qq*64+nt*16+c16], partial over kv-half kh
  f32x4 oacc[4][4] = {};
  float lacc[4] = {0.f,0.f,0.f,0.f};

  // staging coords: 512 threads, 2 K chunks + 2 V chunks each (r3 flow)
  int kr0 = t >> 3, kc0 = (t & 7) * 8;     // K rows kr0, kr0+64
  int vd0 = t >> 4, vc0 = (t & 15) * 8;    // V d-rows vd0, vd0+32
  // V interleaved column base for this thread's 8-kv chunk (verified r6)
  int m16s = vc0 >> 4, b8 = vc0 & 8;
  int vwb = (m16s >> 1)*32 + (m16s & 1)*4 + b8*2;
  const u16* kga = kg + (rowbase + kr0)*DM + h*64 + kc0;
  const u16* vga = vbase + (size_t)vd0*S_ + vc0;

  for (int kv0 = 0; kv0 < S_; kv0 += 128){
    __syncthreads();                       // previous tiles fully consumed
    {
      s16x8 k0v = *(const s16x8*)(kga + (size_t)kv0*DM);
      s16x8 k1v = *(const s16x8*)(kga + (size_t)(kv0+64)*DM);
      union { s16x8 v; s16x4 h2[2]; } v0v, v1v;
      v0v.v = *(const s16x8*)(vga + kv0);
      v1v.v = *(const s16x8*)(vga + (size_t)32*S_ + kv0);
      *(s16x8*)&Kb[kr0*KST + kc0]      = k0v;
      *(s16x8*)&Kb[(kr0+64)*KST + kc0] = k1v;
      *(s16x4*)&Vb[vd0*VST + vwb]          = v0v.h2[0];
      *(s16x4*)&Vb[vd0*VST + vwb + 8]      = v0v.h2[1];
      *(s16x4*)&Vb[(vd0+32)*VST + vwb]     = v1v.h2[0];
      *(s16x4*)&Vb[(vd0+32)*VST + vwb + 8] = v1v.h2[1];
    }
    __syncthreads();

    #pragma unroll
    for (int mtp=0; mtp<2; mtp++){         // pair of 16-kv strips
      uint32_t pk[2][4][2];
      #pragma unroll
      for (int ml=0; ml<2; ml++){
        int mt = mtp*2 + ml;
        // S^T strip: kv = kh*64 + mt*16 + quad*4 + r, q = qq*64 + nt*16 + c16
        f32x4 sc[4] = {};
        #pragma unroll
        for (int ks=0;ks<2;ks++){
          s16x8 kf = *(const s16x8*)&Kb[(kh*64 + mt*16 + c16)*KST + ks*32 + quad*8];
          #pragma unroll
          for (int nt=0;nt<4;nt++)
            sc[nt] = __builtin_amdgcn_mfma_f32_16x16x32_bf16(kf, qf[nt][ks], sc[nt], 0,0,0);
        }
        #pragma unroll
        for (int nt=0;nt<4;nt++){
          float p0 = __builtin_amdgcn_exp2f(sc[nt][0]);
          float p1 = __builtin_amdgcn_exp2f(sc[nt][1]);
          float p2 = __builtin_amdgcn_exp2f(sc[nt][2]);
          float p3 = __builtin_amdgcn_exp2f(sc[nt][3]);
          lacc[nt] += (p0 + p1) + (p2 + p3);
          pk[ml][nt][0] = pkbf(p0, p1);
          pk[ml][nt][1] = pkbf(p2, p3);
        }
      }
      // O^T += V^T P^T for both strips; V-frag is one b128 (interleaved layout)
      #pragma unroll
      for (int dt=0;dt<4;dt++){
        union { s16x8 v; s16x4 h2[2]; } vf;
        vf.v = *(const s16x8*)&Vb[(dt*16 + c16)*VST + (kh*2 + mtp)*32 + quad*8];
        #pragma unroll
        for (int nt=0;nt<4;nt++){
          union { uint32_t u[2]; s16x4 v; } pA, pB;
          pA.u[0] = pk[0][nt][0]; pA.u[1] = pk[0][nt][1];
          pB.u[0] = pk[1][nt][0]; pB.u[1] = pk[1][nt][1];
          oacc[dt][nt] = MFMA16(vf.h2[0], pA.v, oacc[dt][nt]);
          oacc[dt][nt] = MFMA16(vf.h2[1], pB.v, oacc[dt][nt]);
        }
      }
    }
  }

  // ---- epilogue: reduce l across quads, merge kv-halves, normalize, store ----
  float lw[4];
  #pragma unroll
  for (int nt=0;nt<4;nt++){
    float l = lacc[nt];
    l += __shfl_xor(l, 16);
    l += __shfl_xor(l, 32);
    lw[nt] = l;
  }
  __syncthreads();                               // phase-1 smem free
  if (quad == 0){
    #pragma unroll
    for (int nt=0;nt<4;nt++) Lb[kh*256 + qq*64 + nt*16 + c16] = lw[nt];
  }
  uint32_t pko[4][4][2];
  float invl[4];
  #pragma unroll
  for (int dh=0; dh<2; dh++){
    if (kh == 1){
      #pragma unroll
      for (int dt2=0;dt2<2;dt2++)
        #pragma unroll
        for (int nt=0;nt<4;nt++)
          *(f32x4*)&Ob[(qq*64 + nt*16 + c16)*36 + dt2*16 + quad*4] = oacc[dh*2+dt2][nt];
    }
    __syncthreads();
    if (kh == 0){
      if (dh == 0){
        #pragma unroll
        for (int nt=0;nt<4;nt++){
          int ql = qq*64 + nt*16 + c16;
          invl[nt] = 1.0f / (Lb[ql] + Lb[256 + ql]);
        }
      }
      #pragma unroll
      for (int dt2=0;dt2<2;dt2++)
        #pragma unroll
        for (int nt=0;nt<4;nt++){
          f32x4 p = *(const f32x4*)&Ob[(qq*64 + nt*16 + c16)*36 + dt2*16 + quad*4];
          f32x4 o = oacc[dh*2+dt2][nt] + p;
          pko[dh*2+dt2][nt][0] = pkbf(o[0]*invl[nt], o[1]*invl[nt]);
          pko[dh*2+dt2][nt][1] = pkbf(o[2]*invl[nt], o[3]*invl[nt]);
        }
    }
    __syncthreads();
  }
  if (kh == 0){
    #pragma unroll
    for (int dt=0;dt<4;dt++)
      #pragma unroll
      for (int nt=0;nt<4;nt++){
        u32x2 pr; pr.x = pko[dt][nt][0]; pr.y = pko[dt][nt][1];
        *(u32x2*)&ObT[(qq*64 + nt*16 + c16)*72 + dt*16 + quad*4] = pr;
      }
  }
  __syncthreads();
  #pragma unroll
  for (int i=0;i<4;i++){
    int idx = t + i*512;
    int qr = idx >> 3, qc = (idx & 7)*8;
    *(s16x8*)(ao + (rowbase + q0 + qr)*DM + h*64 + qc) = *(const s16x8*)&ObT[qr*72 + qc];
  }
}

extern "C" void kernel_launch(void* const* d_in, const int* in_sizes, int n_in,
                              void* d_out, int out_size, void* d_ws, size_t ws_size,
                              hipStream_t stream){
  const float* x  = (const float*)d_in[0];
  const float* Wq = (const float*)d_in[1];
  const float* bq = (const float*)d_in[2];
  const float* Wk = (const float*)d_in[3];
  const float* bk = (const float*)d_in[4];
  const float* Wv = (const float*)d_in[5];
  const float* bv = (const float*)d_in[6];
  const float* Wo = (const float*)d_in[7];
  const float* bo = (const float*)d_in[8];

  char* ws = (char*)d_ws;
  const size_t XB = (size_t)M_TOT*DM*2;          // 16 MiB per activation buffer
  const size_t WTB = (size_t)4*DM*DM*2;          // 8 MiB for 4 transposed weights
  u16* xb  = (u16*)(ws);
  u16* wt  = (u16*)(ws + XB);
  u16* qb  = (u16*)(ws + XB + WTB);
  u16* kb  = (u16*)(ws + XB + WTB + XB);
  u16* vb  = (u16*)(ws + XB + WTB + 2*XB);
  u16* vtb = (u16*)(ws + XB + WTB + 3*XB);
  u16* aob = (u16*)(ws + XB + WTB + 4*XB);

  k_cvt_x<<<dim3((M_TOT*DM)/(256*8)), 256, 0, stream>>>(x, xb);
  k_wt<<<dim3(16,16,4), 256, 0, stream>>>(Wq, Wk, Wv, Wo, wt);
  k_gemm_qkv<<<dim3(8, M_TOT/128, 3), 256, 0, stream>>>(xb, wt, bq, bk, bv, qb, kb, vb);
  k_vt<<<dim3(S_/64, H_, B_), 256, 0, stream>>>(vb, vtb);
  k_attn<<<dim3(S_/256, H_, B_), 512, 0, stream>>>(qb, kb, vtb, aob);
  k_gemm_out<<<dim3(8, M_TOT/128), 256, 0, stream>>>(aob, wt + (size_t)3*DM*DM, bo, (float*)d_out);
}

// Round 8
// 379.504 us; speedup vs baseline: 1.3738x; 1.3738x over previous
//
#include <hip/hip_runtime.h>
#include <hip/hip_bf16.h>
#include <stdint.h>

#define B_ 2
#define S_ 4096
#define DM 1024
#define H_ 16
#define HD 64
#define M_TOT (B_*S_)   // 8192

typedef unsigned short u16;
typedef short s16x8 __attribute__((ext_vector_type(8)));
typedef short s16x4 __attribute__((ext_vector_type(4)));
typedef float f32x4 __attribute__((ext_vector_type(4)));
typedef uint32_t u32x2 __attribute__((ext_vector_type(2)));

// ---- mfma_f32_16x16x16_bf16 (K=16) ----
#if __has_builtin(__builtin_amdgcn_mfma_f32_16x16x16_bf16)
#define MFMA16(A,B,C) __builtin_amdgcn_mfma_f32_16x16x16_bf16(A,B,C,0,0,0)
#elif __has_builtin(__builtin_amdgcn_mfma_f32_16x16x16bf16_1k)
#define MFMA16(A,B,C) __builtin_amdgcn_mfma_f32_16x16x16bf16_1k(A,B,C,0,0,0)
#else
static __device__ __forceinline__ f32x4 mfma16_asm(s16x4 a, s16x4 b, f32x4 c){
  f32x4 d;
  asm volatile("v_mfma_f32_16x16x16_bf16 %0, %1, %2, %3" : "=v"(d) : "v"(a), "v"(b), "v"(c));
  return d;
}
#define MFMA16(A,B,C) mfma16_asm(A,B,C)
#endif

__device__ __forceinline__ u16 f2bf(float f){
  union { float fv; uint32_t u; } x; x.fv = f;
  uint32_t r = (x.u + 0x7fffu + ((x.u >> 16) & 1u)) >> 16;
  return (u16)r;
}

// pack two f32 -> bf16x2 (a -> low 16, b -> high 16)
#if __has_builtin(__builtin_amdgcn_cvt_pk_bf16_f32)
typedef __bf16 bf16x2_t __attribute__((ext_vector_type(2)));
__device__ __forceinline__ uint32_t pkbf(float a, float b){
  union { bf16x2_t v; uint32_t u; } x;
  x.v = __builtin_amdgcn_cvt_pk_bf16_f32(a, b);
  return x.u;
}
#else
__device__ __forceinline__ uint32_t pkbf(float a, float b){
  union { float f; uint32_t u; } xa, xb; xa.f = a; xb.f = b;
  return __builtin_amdgcn_perm(xb.u + 0x8000u, xa.u + 0x8000u, 0x07060302u);
}
#endif

__device__ __forceinline__ void gld_lds16(const void* g, void* l){
  __builtin_amdgcn_global_load_lds((const __attribute__((address_space(1))) void*)g,
                                   (__attribute__((address_space(3))) void*)l, 16, 0, 0);
}

// ---------------- convert x (fp32) -> bf16 ----------------
__global__ __launch_bounds__(256) void k_cvt_x(const float* __restrict__ x, u16* __restrict__ xb){
  size_t i = (size_t)blockIdx.x * 256 + threadIdx.x;
  const float4* p = (const float4*)x + i*2;
  float4 a = p[0], b = p[1];
  union { u16 u[8]; uint4 v; } o;
  o.u[0]=f2bf(a.x); o.u[1]=f2bf(a.y); o.u[2]=f2bf(a.z); o.u[3]=f2bf(a.w);
  o.u[4]=f2bf(b.x); o.u[5]=f2bf(b.y); o.u[6]=f2bf(b.z); o.u[7]=f2bf(b.w);
  ((uint4*)xb)[i] = o.v;
}

// ------- transpose + convert W [K][N] f32 -> WT [N][K] bf16 (4 mats) -------
__global__ __launch_bounds__(256) void k_wt(const float* __restrict__ W0, const float* __restrict__ W1,
                                            const float* __restrict__ W2, const float* __restrict__ W3,
                                            u16* __restrict__ wt){
  const float* W = blockIdx.z==0?W0: blockIdx.z==1?W1: blockIdx.z==2?W2:W3;
  u16* out = wt + (size_t)blockIdx.z * DM * DM;
  int n0 = blockIdx.x*64, k0 = blockIdx.y*64;
  __shared__ u16 T[64*66];
  int t = threadIdx.x;
  #pragma unroll
  for (int i=0;i<4;i++){
    int idx = t + i*256;
    int kr = idx >> 4, n4 = idx & 15;
    float4 v = *(const float4*)(W + (size_t)(k0+kr)*DM + n0 + n4*4);
    T[(n4*4+0)*66 + kr] = f2bf(v.x);
    T[(n4*4+1)*66 + kr] = f2bf(v.y);
    T[(n4*4+2)*66 + kr] = f2bf(v.z);
    T[(n4*4+3)*66 + kr] = f2bf(v.w);
  }
  __syncthreads();
  #pragma unroll
  for (int i=0;i<2;i++){
    int idx = t + i*256;
    int n = idx >> 3, k8 = idx & 7;
    union { u16 u[8]; uint4 v; } o;
    #pragma unroll
    for (int j=0;j<8;j++) o.u[j] = T[n*66 + k8*8 + j];
    *(uint4*)(out + (size_t)(n0+n)*DM + k0 + k8*8) = o.v;
  }
}

// ---------------- 128x128 MFMA GEMM, A[M,K] bf16 row-major, BT[N,K] bf16 ----------------
__device__ __forceinline__ void gemm128(const u16* __restrict__ A, const u16* __restrict__ BT,
                                        const float* __restrict__ bias, float scale,
                                        u16* __restrict__ outb, float* __restrict__ outf,
                                        int m0, int n0){
  __shared__ __align__(16) u16 As[128*32];
  __shared__ __align__(16) u16 Bs[128*32];
  int t = threadIdx.x;
  int lane = t & 63, w = t >> 6;
  int wm = w & 1, wn = w >> 1;
  int c16 = lane & 15, quad = lane >> 4;
  f32x4 acc[4][4] = {};
  for (int k0 = 0; k0 < DM; k0 += 32){
    #pragma unroll
    for (int i=0;i<2;i++){
      int idx = t + i*256;
      int row = idx >> 2, c8 = (idx & 3) << 3;
      gld_lds16(A  + (size_t)(m0+row)*DM + k0 + c8, &As[idx*8]);
      gld_lds16(BT + (size_t)(n0+row)*DM + k0 + c8, &Bs[idx*8]);
    }
    __syncthreads();
    s16x8 af[4], bf[4];
    #pragma unroll
    for (int mi=0;mi<4;mi++) af[mi] = *(const s16x8*)&As[(wm*64+mi*16+c16)*32 + quad*8];
    #pragma unroll
    for (int ni=0;ni<4;ni++) bf[ni] = *(const s16x8*)&Bs[(wn*64+ni*16+c16)*32 + quad*8];
    #pragma unroll
    for (int mi=0;mi<4;mi++)
      #pragma unroll
      for (int ni=0;ni<4;ni++)
        acc[mi][ni] = __builtin_amdgcn_mfma_f32_16x16x32_bf16(af[mi], bf[ni], acc[mi][ni], 0, 0, 0);
    __syncthreads();
  }
  #pragma unroll
  for (int mi=0;mi<4;mi++){
    #pragma unroll
    for (int ni=0;ni<4;ni++){
      int col = n0 + wn*64 + ni*16 + c16;
      float bc = bias[col];
      #pragma unroll
      for (int r=0;r<4;r++){
        int row = m0 + wm*64 + mi*16 + quad*4 + r;
        float v = (acc[mi][ni][r] + bc) * scale;
        if (outb) outb[(size_t)row*DM + col] = f2bf(v);
        else      outf[(size_t)row*DM + col] = v;
      }
    }
  }
}

#define CL2 0.18033688011112042f   // log2(e)/sqrt(64)

__global__ __launch_bounds__(256) void k_gemm_qkv(const u16* __restrict__ xb, const u16* __restrict__ wt,
                                                  const float* __restrict__ b0, const float* __restrict__ b1,
                                                  const float* __restrict__ b2,
                                                  u16* __restrict__ q, u16* __restrict__ k, u16* __restrict__ v){
  int z = blockIdx.z;
  const u16* BT = wt + (size_t)z*DM*DM;
  const float* bias = z==0?b0: z==1?b1:b2;
  u16* out = z==0?q: z==1?k:v;
  float scale = (z==0) ? CL2 : 1.0f;   // fold softmax scale+log2e into Q
  gemm128(xb, BT, bias, scale, out, nullptr, blockIdx.y*128, blockIdx.x*128);
}

__global__ __launch_bounds__(256) void k_gemm_out(const u16* __restrict__ ab, const u16* __restrict__ wto,
                                                  const float* __restrict__ bias, float* __restrict__ out){
  gemm128(ab, wto, bias, 1.0f, nullptr, out, blockIdx.y*128, blockIdx.x*128);
}

// ---------------- transpose V [B*S, H*64] -> VT [B,H,64,S] ----------------
__global__ __launch_bounds__(256) void k_vt(const u16* __restrict__ vb, u16* __restrict__ vt){
  __shared__ u16 T[64*66];   // [d][s]
  int s0 = blockIdx.x*64, h = blockIdx.y, b = blockIdx.z;
  int t = threadIdx.x;
  #pragma unroll
  for (int i=0;i<2;i++){
    int idx = t + i*256;
    int sr = idx >> 3, d8 = idx & 7;
    s16x8 v = *(const s16x8*)(vb + ((size_t)(b*S_ + s0 + sr))*DM + h*64 + d8*8);
    #pragma unroll
    for (int j=0;j<8;j++) T[(d8*8+j)*66 + sr] = ((const u16*)&v)[j];
  }
  __syncthreads();
  #pragma unroll
  for (int i=0;i<2;i++){
    int idx = t + i*256;
    int d = idx >> 3, s8 = idx & 7;
    union { u16 u[8]; uint4 v; } o;
    #pragma unroll
    for (int j=0;j<8;j++) o.u[j] = T[d*66 + s8*8 + j];
    *(uint4*)(vt + ((size_t)((b*H_ + h)*64 + d))*S_ + s0 + s8*8) = o.v;
  }
}

// ---------------- flash attention v8 = round-3 kernel EXACTLY, minus VALU ----
// Byte-identical structure to v3 (203 us measured: strides 72/136, b128
// staging, full sc[4][4] -> exp -> PV with b64 V-frags, 2 barriers/iter).
// ONLY deltas: (1) CL2 pre-folded into Q at GEMM time (removes 64 v_mul/iter),
// (2) pkbf via v_cvt_pk_bf16_f32 (1 op/pair vs 3).
__global__ __launch_bounds__(512, 2) void k_attn(const u16* __restrict__ qg, const u16* __restrict__ kg,
                                                 const u16* __restrict__ vtg, u16* __restrict__ ao){
  __shared__ __align__(16) char smem[38912];
  u16*   Kb  = (u16*)smem;                 // [128 kv][72]   (phase 1)
  u16*   Vb  = (u16*)(smem + 18432);       // [64 d][136]    (phase 1)
  float* Ob  = (float*)smem;               // [256 q][36]    (epilogue)
  u16*   ObT = (u16*)smem;                 // [256 q][72]    (epilogue)
  float* Lb  = (float*)(smem + 36864);     // [2][256]

  int t = threadIdx.x, lane = t & 63, w = t >> 6;
  int c16 = lane & 15, quad = lane >> 4;
  int qq = w & 3, kh = w >> 2;
  int h = blockIdx.y, b = blockIdx.z;
  int q0 = blockIdx.x * 256;
  size_t rowbase = (size_t)b * S_;
  const u16* vbase = vtg + ((size_t)(b*H_ + h)) * 64 * S_;

  // persistent Q B-frags (pre-scaled by CL2): q = q0+qq*64+nt*16+c16, k = ks*32+quad*8
  s16x8 qf[4][2];
  #pragma unroll
  for (int nt=0;nt<4;nt++)
    #pragma unroll
    for (int ks=0;ks<2;ks++)
      qf[nt][ks] = *(const s16x8*)(qg + (rowbase + q0 + qq*64 + nt*16 + c16)*DM + h*64 + ks*32 + quad*8);

  // oacc[dt][nt]: O^T[d=dt*16+quad*4+r][q=qq*64+nt*16+c16], partial over kv-half kh
  f32x4 oacc[4][4] = {};
  float lacc[4] = {0.f,0.f,0.f,0.f};

  for (int kv0 = 0; kv0 < S_; kv0 += 128){
    __syncthreads();
    // stage K tile [128 kv][64 d] (stride 72) and VT tile [64 d][128 kv] (stride 136)
    #pragma unroll
    for (int i=0;i<2;i++){
      int idx = t + i*512;
      int kr = idx >> 3, kc = (idx & 7)*8;
      *(s16x8*)&Kb[kr*72 + kc] = *(const s16x8*)(kg + (rowbase + kv0 + kr)*DM + h*64 + kc);
      int vd = idx >> 4, vc = (idx & 15)*8;
      *(s16x8*)&Vb[vd*136 + vc] = *(const s16x8*)(vbase + (size_t)vd*S_ + kv0 + vc);
    }
    __syncthreads();

    // S^T tile: kv = kh*64 + mt*16 + quad*4 + r, q = qq*64 + nt*16 + c16
    f32x4 sc[4][4] = {};
    #pragma unroll
    for (int mt=0;mt<4;mt++){
      #pragma unroll
      for (int ks=0;ks<2;ks++){
        s16x8 kf = *(const s16x8*)&Kb[(kh*64 + mt*16 + c16)*72 + ks*32 + quad*8];
        #pragma unroll
        for (int nt=0;nt<4;nt++)
          sc[mt][nt] = __builtin_amdgcn_mfma_f32_16x16x32_bf16(kf, qf[nt][ks], sc[mt][nt], 0,0,0);
      }
    }

    // p = exp2(s) (scale pre-folded into Q); accumulate per-lane l; pack to bf16
    uint32_t pk[4][4][2];
    #pragma unroll
    for (int mt=0;mt<4;mt++){
      #pragma unroll
      for (int nt=0;nt<4;nt++){
        float p0 = __builtin_amdgcn_exp2f(sc[mt][nt][0]);
        float p1 = __builtin_amdgcn_exp2f(sc[mt][nt][1]);
        float p2 = __builtin_amdgcn_exp2f(sc[mt][nt][2]);
        float p3 = __builtin_amdgcn_exp2f(sc[mt][nt][3]);
        lacc[nt] += (p0 + p1) + (p2 + p3);
        pk[mt][nt][0] = pkbf(p0, p1);
        pk[mt][nt][1] = pkbf(p2, p3);
      }
    }

    // O^T += V^T P^T : A = V^T frag (m=d=c16, k=quad*4+j), B = pk
    #pragma unroll
    for (int mt=0;mt<4;mt++){
      #pragma unroll
      for (int dt=0;dt<4;dt++){
        s16x4 vf = *(const s16x4*)&Vb[(dt*16 + c16)*136 + kh*64 + mt*16 + quad*4];
        #pragma unroll
        for (int nt=0;nt<4;nt++){
          union { uint32_t u[2]; s16x4 v; } pp;
          pp.u[0] = pk[mt][nt][0]; pp.u[1] = pk[mt][nt][1];
          oacc[dt][nt] = MFMA16(vf, pp.v, oacc[dt][nt]);
        }
      }
    }
  }

  // ---- epilogue: reduce l across quads, merge kv-halves, normalize, store ----
  float lw[4];
  #pragma unroll
  for (int nt=0;nt<4;nt++){
    float l = lacc[nt];
    l += __shfl_xor(l, 16);
    l += __shfl_xor(l, 32);
    lw[nt] = l;
  }
  __syncthreads();                               // phase-1 smem free
  if (quad == 0){
    #pragma unroll
    for (int nt=0;nt<4;nt++) Lb[kh*256 + qq*64 + nt*16 + c16] = lw[nt];
  }
  uint32_t pko[4][4][2];
  float invl[4];
  #pragma unroll
  for (int dh=0; dh<2; dh++){
    if (kh == 1){
      #pragma unroll
      for (int dt2=0;dt2<2;dt2++)
        #pragma unroll
        for (int nt=0;nt<4;nt++)
          *(f32x4*)&Ob[(qq*64 + nt*16 + c16)*36 + dt2*16 + quad*4] = oacc[dh*2+dt2][nt];
    }
    __syncthreads();
    if (kh == 0){
      if (dh == 0){
        #pragma unroll
        for (int nt=0;nt<4;nt++){
          int ql = qq*64 + nt*16 + c16;
          invl[nt] = 1.0f / (Lb[ql] + Lb[256 + ql]);
        }
      }
      #pragma unroll
      for (int dt2=0;dt2<2;dt2++)
        #pragma unroll
        for (int nt=0;nt<4;nt++){
          f32x4 p = *(const f32x4*)&Ob[(qq*64 + nt*16 + c16)*36 + dt2*16 + quad*4];
          f32x4 o = oacc[dh*2+dt2][nt] + p;
          pko[dh*2+dt2][nt][0] = pkbf(o[0]*invl[nt], o[1]*invl[nt]);
          pko[dh*2+dt2][nt][1] = pkbf(o[2]*invl[nt], o[3]*invl[nt]);
        }
    }
    __syncthreads();
  }
  if (kh == 0){
    #pragma unroll
    for (int dt=0;dt<4;dt++)
      #pragma unroll
      for (int nt=0;nt<4;nt++){
        u32x2 pr; pr.x = pko[dt][nt][0]; pr.y = pko[dt][nt][1];
        *(u32x2*)&ObT[(qq*64 + nt*16 + c16)*72 + dt*16 + quad*4] = pr;
      }
  }
  __syncthreads();
  #pragma unroll
  for (int i=0;i<4;i++){
    int idx = t + i*512;
    int qr = idx >> 3, qc = (idx & 7)*8;
    *(s16x8*)(ao + (rowbase + q0 + qr)*DM + h*64 + qc) = *(const s16x8*)&ObT[qr*72 + qc];
  }
}

extern "C" void kernel_launch(void* const* d_in, const int* in_sizes, int n_in,
                              void* d_out, int out_size, void* d_ws, size_t ws_size,
                              hipStream_t stream){
  const float* x  = (const float*)d_in[0];
  const float* Wq = (const float*)d_in[1];
  const float* bq = (const float*)d_in[2];
  const float* Wk = (const float*)d_in[3];
  const float* bk = (const float*)d_in[4];
  const float* Wv = (const float*)d_in[5];
  const float* bv = (const float*)d_in[6];
  const float* Wo = (const float*)d_in[7];
  const float* bo = (const float*)d_in[8];

  char* ws = (char*)d_ws;
  const size_t XB = (size_t)M_TOT*DM*2;          // 16 MiB per activation buffer
  const size_t WTB = (size_t)4*DM*DM*2;          // 8 MiB for 4 transposed weights
  u16* xb  = (u16*)(ws);
  u16* wt  = (u16*)(ws + XB);
  u16* qb  = (u16*)(ws + XB + WTB);
  u16* kb  = (u16*)(ws + XB + WTB + XB);
  u16* vb  = (u16*)(ws + XB + WTB + 2*XB);
  u16* vtb = (u16*)(ws + XB + WTB + 3*XB);
  u16* aob = (u16*)(ws + XB + WTB + 4*XB);

  k_cvt_x<<<dim3((M_TOT*DM)/(256*8)), 256, 0, stream>>>(x, xb);
  k_wt<<<dim3(16,16,4), 256, 0, stream>>>(Wq, Wk, Wv, Wo, wt);
  k_gemm_qkv<<<dim3(8, M_TOT/128, 3), 256, 0, stream>>>(xb, wt, bq, bk, bv, qb, kb, vb);
  k_vt<<<dim3(S_/64, H_, B_), 256, 0, stream>>>(vb, vtb);
  k_attn<<<dim3(S_/256, H_, B_), 512, 0, stream>>>(qb, kb, vtb, aob);
  k_gemm_out<<<dim3(8, M_TOT/128), 256, 0, stream>>>(aob, wt + (size_t)3*DM*DM, bo, (float*)d_out);
}